// Round 11
// baseline (291.862 us; speedup 1.0000x reference)
//
#include <hip/hip_runtime.h>
#include <cfloat>
#include <math.h>

// Exact-replication KNN (k=10, +self) + rank-column gather max-pool.
// NUMERICS FROZEN (R3 pass, absmax 0.0): fp32 chains
//   sq  = fma(z,z, fma(y,y, rn(x*x)))
//   dot = fma(z,z', fma(y,y', rn(x*x')))
//   d   = fma(dot, -2, rn(sq_i+sq_j))    [== rn(sum - rn(2*dot)), 2*dot exact]
// Selection order = jax top_k = ascending lexicographic (d, orig_idx) —
// proven order-independent in R8/R9/R10 (absmax 0.0, nondeterministic sort).
//
// Round 11: ascending-lb tile scan via on-the-fly min-extraction.
//  - Each lane privately holds survivor entries for tiles {lane, 64+lane}
//    packed as (lb_bits & ~0xFF)|tile (lb>=0 -> uint order == lb order;
//    unpacked lb rounds DOWN -> conservative). No LDS list, no build pass.
//  - Per iteration: 6-step shfl_xor u32-min butterfly extracts the nearest
//    remaining tile; owner lane clears its entry. Processing in ascending
//    lb order tightens worst maximally fast, and when
//    min_lb - 1e-3 > current wmax, ALL remaining tiles are pruned at once
//    (the optimal sound stop; R10's zigzag order processed far tiles
//    before worst was tight — that was the 51%-busy straggler tail).
//  - One-deep register prefetch kept: extraction order is data-independent
//    of processing, so the next tile's batches load while current computes.

#define N_PTS    16384
#define C_FEAT   64
#define KK       11
#define NCELLS   4096                 // 16^3 Morton cells
#define TILE     128                  // sorted points per tile
#define NTILES   (N_PTS / TILE)       // 128
#define WQ       4
#define NWAVES   4
#define NTHREADS (NWAVES * 64)
#define QPB      (NWAVES * WQ)        // 16 queries per block
#define SENT     0xFFFFFFFFu

// d_ws layout (bytes)
#define WS_CAND  0                          // float4[2][N_PTS]   512 KB
#define WS_AABB  (WS_CAND + 2*N_PTS*16)     // float[2][NTILES][6]

__device__ __forceinline__ int cell_of(float x, float y, float z) {
    int cx = (int)floorf((x + 4.5f) * (16.0f / 9.0f));
    int cy = (int)floorf((y + 4.5f) * (16.0f / 9.0f));
    int cz = (int)floorf((z + 4.5f) * (16.0f / 9.0f));
    cx = min(15, max(0, cx));
    cy = min(15, max(0, cy));
    cz = min(15, max(0, cz));
    int m = 0;
    #pragma unroll
    for (int b = 0; b < 4; ++b)
        m |= (((cx >> b) & 1) << (3 * b)) |
             (((cy >> b) & 1) << (3 * b + 1)) |
             (((cz >> b) & 1) << (3 * b + 2));
    return m;
}

// Fused hist + scan + scatter. One block per instance, 1024 threads.
__global__ __launch_bounds__(1024) void sort_kernel(
    const float* __restrict__ src_c, const float* __restrict__ tgt_c,
    float4* __restrict__ cand)
{
    const int inst = blockIdx.x;
    const float* __restrict__ coords = inst ? tgt_c : src_c;
    float4* __restrict__ cb = cand + inst * N_PTS;

    __shared__ int hist[NCELLS];   // becomes running write-pointer after scan
    __shared__ int sd[1024];
    const int t = threadIdx.x;

    for (int i = t; i < NCELLS; i += 1024) hist[i] = 0;
    __syncthreads();

    int mycell[16];
    #pragma unroll
    for (int j = 0; j < 16; ++j) {
        const int p = j * 1024 + t;
        const float* c = coords + (size_t)p * 3;
        mycell[j] = cell_of(c[0], c[1], c[2]);
        atomicAdd(&hist[mycell[j]], 1);
    }
    __syncthreads();

    int v[4], ssum = 0;
    #pragma unroll
    for (int j = 0; j < 4; ++j) { v[j] = hist[t * 4 + j]; ssum += v[j]; }
    sd[t] = ssum;
    __syncthreads();
    for (int off = 1; off < 1024; off <<= 1) {
        const int x = (t >= off) ? sd[t - off] : 0;
        __syncthreads();
        sd[t] += x;
        __syncthreads();
    }
    int base = sd[t] - ssum;
    #pragma unroll
    for (int j = 0; j < 4; ++j) { hist[t * 4 + j] = base; base += v[j]; }
    __syncthreads();

    #pragma unroll
    for (int j = 0; j < 16; ++j) {
        const int p = j * 1024 + t;
        const float* c = coords + (size_t)p * 3;
        const int dst = atomicAdd(&hist[mycell[j]], 1);
        cb[dst] = make_float4(c[0], c[1], c[2], __int_as_float(p));
    }
}

__global__ void aabb_kernel(const float4* __restrict__ cand,
                            float* __restrict__ aabb) {
    const int it = blockIdx.x;                 // inst*NTILES + tile
    const int base = (it / NTILES) * N_PTS + (it % NTILES) * TILE;
    const int lane = threadIdx.x;              // 64 threads, 2 pts each
    float4 a = cand[base + lane], b = cand[base + 64 + lane];
    float mnx = fminf(a.x, b.x), mny = fminf(a.y, b.y), mnz = fminf(a.z, b.z);
    float mxx = fmaxf(a.x, b.x), mxy = fmaxf(a.y, b.y), mxz = fmaxf(a.z, b.z);
    #pragma unroll
    for (int off = 1; off < 64; off <<= 1) {
        mnx = fminf(mnx, __shfl_xor(mnx, off));
        mny = fminf(mny, __shfl_xor(mny, off));
        mnz = fminf(mnz, __shfl_xor(mnz, off));
        mxx = fmaxf(mxx, __shfl_xor(mxx, off));
        mxy = fmaxf(mxy, __shfl_xor(mxy, off));
        mxz = fmaxf(mxz, __shfl_xor(mxz, off));
    }
    if (lane == 0) {
        aabb[it * 6 + 0] = mnx; aabb[it * 6 + 1] = mny; aabb[it * 6 + 2] = mnz;
        aabb[it * 6 + 3] = mxx; aabb[it * 6 + 4] = mxy; aabb[it * 6 + 5] = mxz;
    }
}

// One 64-candidate batch vs the wave's 4 queries (proven R8-R10).
#define PROCESS_BATCH(C, INIT)                                              \
  {                                                                         \
    const float cx = (C).x, cy = (C).y, cz = (C).z;                         \
    const int corig = __float_as_int((C).w);                                \
    const float csq = __fmaf_rn(cz, cz, __fmaf_rn(cy, cy,                   \
                                __fmul_rn(cx, cx)));                        \
    _Pragma("unroll")                                                       \
    for (int q = 0; q < WQ; ++q) {                                          \
      float dot = __fmul_rn(cx, qx[q]);                                     \
      dot = __fmaf_rn(cy, qy[q], dot);                                      \
      dot = __fmaf_rn(cz, qz[q], dot);                                      \
      const float sum = __fadd_rn(qsq[q], csq);                             \
      const float d = __fmaf_rn(dot, -2.0f, sum);                           \
      if (INIT) {                                                           \
        float t16 = d;                                                      \
        _Pragma("unroll")                                                   \
        for (int off = 1; off < 16; off <<= 1)                              \
          t16 = fmaxf(t16, __shfl_xor(t16, off));                           \
        worst[q] = __int_as_float(__builtin_amdgcn_readlane(                \
            __float_as_int(t16), q * 16));                                  \
      }                                                                     \
      unsigned long long m = __ballot(d <= worst[q]);                       \
      while (m) {                                                           \
        const int sl = (int)__builtin_ctzll(m);                             \
        m &= m - 1;                                                         \
        const float nd = __int_as_float(__builtin_amdgcn_readlane(          \
            __float_as_int(d), sl));                                        \
        if (nd <= worst[q]) {                                               \
          const int norig = __builtin_amdgcn_readlane(corig, sl);           \
          const float pld = __int_as_float(                                 \
              __builtin_amdgcn_ds_bpermute(upaddr, __float_as_int(ld)));    \
          const int pli = __builtin_amdgcn_ds_bpermute(upaddr, li);         \
          const bool gt = (ld > nd) || (ld == nd && li > norig);            \
          if (ingrp[q] && gt) {                                             \
            const bool pgt = (pld > nd) || (pld == nd && pli > norig);      \
            const bool fst = (lrank == 0) || (!pgt);                        \
            ld = fst ? nd : pld;                                            \
            li = fst ? norig : pli;                                         \
          }                                                                 \
          worst[q] = fminf(worst[q],                                        \
              __int_as_float(__builtin_amdgcn_readlane(                     \
                  __float_as_int(ld), q * 16 + (KK - 1))));                 \
        }                                                                   \
      }                                                                     \
    }                                                                       \
  }

#define WMAX4 fmaxf(fmaxf(worst[0], worst[1]), fmaxf(worst[2], worst[3]))

__global__ __launch_bounds__(NTHREADS) void knn_pool_kernel(
    const float* __restrict__ src_f, const float* __restrict__ tgt_f,
    const float4* __restrict__ cand, const float* __restrict__ aabb,
    float* __restrict__ out)
{
    const int inst = blockIdx.x & 1;
    const float* __restrict__ feats = inst ? tgt_f : src_f;
    float* __restrict__ outb = out + (size_t)inst * N_PTS * (2 * C_FEAT);
    const float4* __restrict__ cd = cand + inst * N_PTS;

    const int tid = threadIdx.x, wave = tid >> 6, lane = tid & 63;
    const int lq = lane >> 4, lrank = lane & 15;
    const bool inlist = (lrank < KK);
    const int upaddr = ((lane + 63) & 63) << 2;   // ds_bpermute: lane-1

    __shared__ float sab[NTILES * 6];             // 3 KB
    for (int i = tid; i < NTILES * 6; i += NTHREADS)
        sab[i] = aabb[inst * NTILES * 6 + i];
    __syncthreads();

    const int q0 = (blockIdx.x >> 1) * QPB + wave * WQ;  // sorted row
    float qx[WQ], qy[WQ], qz[WQ], qsq[WQ];
    int qor[WQ]; bool ingrp[WQ]; float worst[WQ];
    float wqmnx = FLT_MAX, wqmny = FLT_MAX, wqmnz = FLT_MAX;
    float wqmxx = -FLT_MAX, wqmxy = -FLT_MAX, wqmxz = -FLT_MAX;
    #pragma unroll
    for (int q = 0; q < WQ; ++q) {
        const float4 c = cd[q0 + q];
        qx[q] = c.x; qy[q] = c.y; qz[q] = c.z;
        qor[q] = __float_as_int(c.w);
        qsq[q] = __fmaf_rn(c.z, c.z, __fmaf_rn(c.y, c.y, __fmul_rn(c.x, c.x)));
        ingrp[q] = inlist && (lq == q);
        worst[q] = FLT_MAX;
        wqmnx = fminf(wqmnx, c.x); wqmxx = fmaxf(wqmxx, c.x);
        wqmny = fminf(wqmny, c.y); wqmxy = fmaxf(wqmxy, c.y);
        wqmnz = fminf(wqmnz, c.z); wqmxz = fmaxf(wqmxz, c.z);
    }

    float ld = FLT_MAX;   // lane-distributed sorted list (lex (d, orig_idx))
    int   li = 0x7fffffff;

    const int ownt = q0 / TILE;   // tile containing the queries

    // ---- own tile first: worst init on batch 0, tighten through batch 1 --
    {
        const float4 c0 = cd[ownt * TILE + lane];
        const float4 c1 = cd[ownt * TILE + 64 + lane];
        PROCESS_BATCH(c0, true);
        PROCESS_BATCH(c1, false);
    }
    const float wmax0 = WMAX4;

    // ---- per-lane survivor entries for tiles {lane, 64+lane} ----
    // entry = (lb_bits & ~0xFF) | tile ; SENT if pruned/own/out-of-range.
    unsigned e0 = SENT, e1 = SENT;
    #pragma unroll
    for (int g = 0; g < 2; ++g) {
        const int t = g * 64 + lane;
        if (t != ownt) {
            const float dx = fmaxf(0.f, fmaxf(sab[t*6+0] - wqmxx, wqmnx - sab[t*6+3]));
            const float dy = fmaxf(0.f, fmaxf(sab[t*6+1] - wqmxy, wqmny - sab[t*6+4]));
            const float dz = fmaxf(0.f, fmaxf(sab[t*6+2] - wqmxz, wqmnz - sab[t*6+5]));
            float lb = dx * dx;
            lb = fmaf(dy, dy, lb);
            lb = fmaf(dz, dz, lb);
            if ((lb - 1e-3f) <= wmax0) {   // margin >> fp32 chain error
                const unsigned pk = (__float_as_uint(lb) & 0xFFFFFF00u)
                                    | (unsigned)t;
                if (g == 0) e0 = pk; else e1 = pk;
            }
        }
    }

    // min-extraction: returns wave-uniform min entry, clears its owner slot.
    auto extract_min = [&]() -> unsigned {
        unsigned mn = (e0 < e1) ? e0 : e1;
        #pragma unroll
        for (int off = 1; off < 64; off <<= 1) {
            const unsigned o = (unsigned)__shfl_xor((int)mn, off);
            mn = (o < mn) ? o : mn;
        }
        if (e0 == mn) e0 = SENT;
        else if (e1 == mn) e1 = SENT;
        return mn;
    };

    // ---- ascending-lb scan with one-deep register prefetch ----
    unsigned ucur = extract_min();
    unsigned unxt = extract_min();
    float4 A0, A1, B0, B1;
    if (ucur != SENT) {
        const int t = (int)(ucur & 0xFFu);
        A0 = cd[t * TILE + lane]; A1 = cd[t * TILE + 64 + lane];
    }
    while (ucur != SENT) {
        // optimal sound stop: nearest remaining tile already too far.
        if (__uint_as_float(ucur & 0xFFFFFF00u) - 1e-3f > WMAX4) break;
        const int tn = (int)((unxt != SENT ? unxt : ucur) & 0xFFu);
        B0 = cd[tn * TILE + lane]; B1 = cd[tn * TILE + 64 + lane];
        PROCESS_BATCH(A0, false);
        PROCESS_BATCH(A1, false);
        ucur = unxt;
        unxt = extract_min();
        A0 = B0; A1 = B1;
    }

    // Rank 0 (lex-smallest: self or -1ulp near-twin) dropped positionally.
    // Ranks 1..10 -> feature columns 0..9. li holds ORIGINAL indices.
    float fv = -FLT_MAX;
    if (inlist && lrank >= 1)
        fv = feats[(size_t)li * C_FEAT + (lrank - 1)];
    #pragma unroll
    for (int off = 1; off < 16; off <<= 1)
        fv = fmaxf(fv, __shfl_xor(fv, off));

    #pragma unroll
    for (int q = 0; q < WQ; ++q) {
        const float M   = __shfl(fv, q * 16);
        const int   row = qor[q];
        const float v   = feats[(size_t)row * C_FEAT + lane];
        outb[(size_t)row * (2 * C_FEAT) + lane]          = v;
        outb[(size_t)row * (2 * C_FEAT) + C_FEAT + lane] = M - v;
    }
}

extern "C" void kernel_launch(void* const* d_in, const int* in_sizes, int n_in,
                              void* d_out, int out_size, void* d_ws, size_t ws_size,
                              hipStream_t stream) {
    const float* src_f = (const float*)d_in[0];
    const float* tgt_f = (const float*)d_in[1];
    const float* src_c = (const float*)d_in[2];
    const float* tgt_c = (const float*)d_in[3];
    float* out = (float*)d_out;

    char* ws = (char*)d_ws;
    float4* cand = (float4*)(ws + WS_CAND);
    float*  aabb = (float*) (ws + WS_AABB);

    hipLaunchKernelGGL(sort_kernel, dim3(2), dim3(1024), 0, stream,
                       src_c, tgt_c, cand);
    hipLaunchKernelGGL(aabb_kernel, dim3(2 * NTILES), dim3(64), 0, stream,
                       cand, aabb);
    hipLaunchKernelGGL(knn_pool_kernel, dim3(2 * (N_PTS / QPB)), dim3(NTHREADS),
                       0, stream, src_f, tgt_f, cand, aabb, out);
}